// Round 1
// 204.559 us; speedup vs baseline: 1.0086x; 1.0086x over previous
//
#include <hip/hip_runtime.h>
#include <hip/hip_bf16.h>
#include <stdint.h>

#define BB 256
#define TT 240
#define CC 512
#define KK 64
#define NCLS 4
#define CHUNK 32
#define NCHUNK 8   // 7 full chunks + 1 half (tvalid=16)
#define THREADS 1024

// Subtiled x layout: x[tb][cb][4][16] bf16, tb = t/4 (8 per chunk), cb = c/16 (32)
// CBS: elems per c-block incl +8 pad  -> 144 B  (bank stride 36 ≡ 4 mod 32)
// TBS: elems per t-block incl +8 pad  -> 4624 B (bank stride ≡ 4 mod 32; 2*TBS ≡ 8)
#define CBS 72
#define TBS 2312
#define XELEMS (8 * TBS)   // 18496 elems = 36992 B per buffer

typedef __attribute__((ext_vector_type(8))) short bf16x8;
typedef __attribute__((ext_vector_type(4))) float f32x4;
typedef __attribute__((ext_vector_type(2))) unsigned int u32x2;

__device__ __forceinline__ unsigned short f2bf(float f) {
    union { float f; unsigned int i; } x; x.f = f;
    unsigned int r = x.i + 0x7FFFu + ((x.i >> 16) & 1u);  // RNE, finite only
    return (unsigned short)(r >> 16);
}
// packed fp32x2 -> bf16x2 (v_cvt_pk_bf16_f32 on gfx950), lo in low half
__device__ __forceinline__ unsigned int pk2cvt(float lo, float hi) {
    union { __hip_bfloat162 h; unsigned int u; } c;
    c.h = __float22bfloat162_rn(float2{lo, hi});
    return c.u;
}
// LDS-only barrier: doesn't drain vmcnt (global prefetch stays in flight)
__device__ __forceinline__ void LB() {
    asm volatile("s_waitcnt lgkmcnt(0)\n\ts_barrier" ::: "memory");
}

struct alignas(16) SMemChunk {
    unsigned short x[2][XELEMS];    // double-buffered subtiled x   (73,984 B)
    float logitsP[2][CHUNK][67];    // k-half partials / plain-a    (17,152 B)
    unsigned short aT[KK][40];      // a' = a*rinv bf16             ( 5,120 B)
    float sumsqP[CHUNK][68];        // per-lane sumsq partials      ( 8,704 B)
};
struct alignas(16) SMemEpi { unsigned short vbuf[KK * CC]; };  // 64 KB
union SMemU { SMemChunk c; SMemEpi e; };

__global__ __launch_bounds__(THREADS, 4) void netvlad_kernel(
    const float* __restrict__ inp,    // [B,T,C]
    const float* __restrict__ convw,  // [K,C]
    const float* __restrict__ cent,   // [K,C]
    const float* __restrict__ fcw,    // [NC, K*C]
    const float* __restrict__ fcb,    // [NC]
    float* __restrict__ out)          // [B,NC]
{
    __shared__ SMemU sm;
    __shared__ float asum[KK];
    __shared__ float ssred[4][KK];
    __shared__ float gred[16];
    __shared__ float fcred[16][NCLS];
    __shared__ float vinv_sh;

    const int tid  = threadIdx.x;
    const int b    = blockIdx.x;
    const int w    = tid >> 6;       // wave 0..15
    const int lane = tid & 63;
    const int grp  = (lane >> 4) & 3;
    const int col  = lane & 15;
    const int cg   = w & 3;          // cluster group (logits/VLAD/epilogue)
    const int th   = (w >> 2) & 1;   // logits t-tile
    const int kh   = w >> 3;         // logits k-half
    const int cq   = w >> 2;         // VLAD c-quarter

    if (tid < KK) asum[tid] = 0.f;

    f32x4 acc[8];
    #pragma unroll
    for (int j = 0; j < 8; ++j) acc[j] = (f32x4){0.f, 0.f, 0.f, 0.f};

    // conv_w slice: clusters 16cg..+16, k-half kh (8 x bf16x8 = 16 VGPRs)
    bf16x8 cw[8];
    #pragma unroll
    for (int s = 0; s < 8; ++s) {
        const float* p = convw + (size_t)(cg * 16 + col) * CC + (kh * 8 + s) * 32 + grp * 8;
        float4 a0 = *(const float4*)p;
        float4 a1 = *(const float4*)(p + 4);
        bf16x8 v;
        v[0] = (short)f2bf(a0.x); v[1] = (short)f2bf(a0.y);
        v[2] = (short)f2bf(a0.z); v[3] = (short)f2bf(a0.w);
        v[4] = (short)f2bf(a1.x); v[5] = (short)f2bf(a1.y);
        v[6] = (short)f2bf(a1.z); v[7] = (short)f2bf(a1.w);
        cw[s] = v;
    }

    const size_t ibase = (size_t)b * (TT * CC);

    // prefetch chunk 0 raw fp32
    float4 r0[2], r1[2];
    #pragma unroll
    for (int i = 0; i < 2; ++i) {
        int g = tid + i * THREADS;
        int t = g >> 6, c8 = (g & 63) << 3;
        const float* p = inp + ibase + (size_t)t * CC + c8;
        r0[i] = *(const float4*)p;
        r1[i] = *(const float4*)(p + 4);
    }

    for (int ch = 0; ch < NCHUNK; ++ch) {
        const int t0 = ch * CHUNK;
        const int tvalid = (TT - t0 < CHUNK) ? (TT - t0) : CHUNK;
        const int buf = ch & 1;
        unsigned short* xb = sm.c.x[buf];

        // ---- phase A: stage regs -> bf16 subtiled LDS + per-lane sumsq partial;
        //      issue next-chunk loads ----
        #pragma unroll
        for (int i = 0; i < 2; ++i) {
            int g = tid + i * THREADS;
            int t = g >> 6, c8 = (g & 63) << 3;   // t wave-uniform (= w + 16i), c8 = lane*8
            float4 u0 = r0[i], u1 = r1[i];
            uint4 val = (uint4){pk2cvt(u0.x, u0.y), pk2cvt(u0.z, u0.w),
                                pk2cvt(u1.x, u1.y), pk2cvt(u1.z, u1.w)};
            float s = u0.x*u0.x + u0.y*u0.y + u0.z*u0.z + u0.w*u0.w
                    + u1.x*u1.x + u1.y*u1.y + u1.z*u1.z + u1.w*u1.w;
            if (t >= tvalid) { val = (uint4){0u,0u,0u,0u}; s = 0.f; }
            int off = (t >> 2) * TBS + (c8 >> 4) * CBS + (t & 3) * 16 + (c8 & 15);
            *(uint4*)&xb[off] = val;
            sm.c.sumsqP[t][lane] = s;          // reduced 64-wide in phase C
        }
        if (ch + 1 < NCHUNK) {
            int nt0 = t0 + CHUNK;
            #pragma unroll
            for (int i = 0; i < 2; ++i) {
                int g = tid + i * THREADS;
                int t = g >> 6, c8 = (g & 63) << 3;
                int gt = nt0 + t; if (gt > TT - 1) gt = TT - 1;  // clamp address only
                const float* p = inp + ibase + (size_t)gt * CC + c8;
                r0[i] = *(const float4*)p;
                r1[i] = *(const float4*)(p + 4);
            }
        }
        LB();  // x + sumsq partials ready

        // ---- phase B: partial logits (all 16 waves, conflict-free subtiled reads) ----
        {
            f32x4 lt = (f32x4){0.f, 0.f, 0.f, 0.f};
            const int t = th * 16 + col;
            const int rb = (t >> 2) * TBS + (t & 3) * 16 + ((grp & 1) << 3);
            #pragma unroll
            for (int s = 0; s < 8; ++s) {
                const bf16x8 bb = *(const bf16x8*)&xb[rb + ((kh * 8 + s) * 2 + (grp >> 1)) * CBS];
                lt = __builtin_amdgcn_mfma_f32_16x16x32_bf16(cw[s], bb, lt, 0, 0, 0);
            }
            #pragma unroll
            for (int r = 0; r < 4; ++r)
                sm.c.logitsP[kh][t][cg * 16 + grp * 4 + r] = lt[r];
        }
        LB();  // logitsP ready

        // ---- phase C: sumsq finish + softmax per t (16 threads/row, threads 0..511) ----
        if (tid < 512) {
            int t = tid >> 4, part = tid & 15;
            float4 sp = *(const float4*)&sm.c.sumsqP[t][part * 4];
            float ss = sp.x + sp.y + sp.z + sp.w;

            float l[4]; float lmax = -1e30f;
            #pragma unroll
            for (int q = 0; q < 4; ++q) {
                l[q] = sm.c.logitsP[0][t][q * 16 + part] +
                       sm.c.logitsP[1][t][q * 16 + part];
                lmax = fmaxf(lmax, l[q]);
            }
            // joint 16-lane reductions (max of raw logits commutes with *rinv since rinv>0)
            #pragma unroll
            for (int m = 1; m < 16; m <<= 1) {
                lmax = fmaxf(lmax, __shfl_xor(lmax, m));
                ss  += __shfl_xor(ss, m);
            }
            float rinv = 1.f / fmaxf(sqrtf(ss), 1e-12f);
            rinv = (t < tvalid) ? rinv : 0.f;
            float m0 = lmax * rinv;
            float es = 0.f;
            #pragma unroll
            for (int q = 0; q < 4; ++q) { l[q] = __expf(l[q] * rinv - m0); es += l[q]; }
            #pragma unroll
            for (int m = 1; m < 16; m <<= 1) es += __shfl_xor(es, m);
            float is = 1.f / es;
            #pragma unroll
            for (int q = 0; q < 4; ++q) {
                float a = l[q] * is;
                sm.c.logitsP[0][t][q * 16 + part] = a;                      // plain a
                sm.c.aT[q * 16 + part][t] = (unsigned short)f2bf(a * rinv); // 0 if masked
            }
        }
        LB();  // aT + plain-a ready

        // ---- phase D: asum + VLAD (B-operand via HW transpose read) ----
        if (tid < KK) {
            float s = 0.f;
            for (int t = 0; t < tvalid; ++t) s += sm.c.logitsP[0][t][tid];
            asum[tid] += s;
        }
        {
            bf16x8 af = *(const bf16x8*)&sm.c.aT[cg * 16 + col][grp * 8];
            // per-lane base: x[buf][tb=grp*2][cb=cq*8][r=0][col]; HW strides r (+32B/elem)
            // gfx9 LDS aperture is 4GB-aligned: low 32 bits of flat ptr = LDS byte offset
            unsigned xvb = (unsigned)(uintptr_t)&xb[(grp * 2) * TBS + (cq * 8) * CBS + col];
            #pragma unroll
            for (int hh = 0; hh < 2; ++hh) {
                u32x2 lo[4], hi[4];
                #pragma unroll
                for (int j2 = 0; j2 < 4; ++j2) {
                    const unsigned o = (unsigned)((hh * 4 + j2) * 2 * CBS);  // jj*144 B
                    asm volatile("ds_read_b64_tr_b16 %0, %1"
                                 : "=v"(lo[j2]) : "v"(xvb + o));                       // t = grp*8+0..3
                    asm volatile("ds_read_b64_tr_b16 %0, %1"
                                 : "=v"(hi[j2]) : "v"(xvb + o + (unsigned)(2 * TBS))); // t = grp*8+4..7
                }
                asm volatile("s_waitcnt lgkmcnt(0)" ::: "memory");
                __builtin_amdgcn_sched_barrier(0);   // rule #18: keep MFMAs below the wait
                #pragma unroll
                for (int j2 = 0; j2 < 4; ++j2) {
                    union { bf16x8 v; u32x2 u[2]; } pk;
                    pk.u[0] = lo[j2]; pk.u[1] = hi[j2];
                    acc[hh * 4 + j2] = __builtin_amdgcn_mfma_f32_16x16x32_bf16(
                        af, pk.v, acc[hh * 4 + j2], 0, 0, 0);
                }
            }
        }
        // no barrier: next phase A writes x[buf^1] + sumsqP (read 2 barriers ago)
    }

    // ===== epilogue =====
    LB();

    // centroid subtract + per-cluster partial sumsq (c-quarter per wave)
    #pragma unroll
    for (int r = 0; r < 4; ++r) {
        int cl = cg * 16 + grp * 4 + r;
        float as = asum[cl];
        float ss = 0.f;
        #pragma unroll
        for (int j = 0; j < 8; ++j) {
            int c = cq * 128 + j * 16 + col;
            float v = acc[j][r] - as * cent[(size_t)cl * CC + c];
            acc[j][r] = v;
            ss += v * v;
        }
        ss += __shfl_xor(ss, 1); ss += __shfl_xor(ss, 2);
        ss += __shfl_xor(ss, 4); ss += __shfl_xor(ss, 8);
        if (col == 0) ssred[cq][cl] = ss;
    }
    LB();

    float contrib = 0.f;
    #pragma unroll
    for (int r = 0; r < 4; ++r) {
        int cl = cg * 16 + grp * 4 + r;
        float ss = ssred[0][cl] + ssred[1][cl] + ssred[2][cl] + ssred[3][cl];
        float inv = 1.f / fmaxf(sqrtf(ss), 1e-12f);
        #pragma unroll
        for (int j = 0; j < 8; ++j) {
            float v = acc[j][r] * inv;
            acc[j][r] = v;
            contrib += v * v;
        }
    }
    #pragma unroll
    for (int m = 1; m < 64; m <<= 1) contrib += __shfl_xor(contrib, m);
    if (lane == 0) gred[w] = contrib;
    LB();
    if (tid == 0) {
        float tot = 0.f;
        #pragma unroll
        for (int i = 0; i < 16; ++i) tot += gred[i];
        vinv_sh = 1.f / fmaxf(sqrtf(tot), 1e-12f);
    }
    LB();

    // write normalized v (bf16) to LDS — chunk arrays dead now
    {
        float vinv = vinv_sh;
        #pragma unroll
        for (int r = 0; r < 4; ++r) {
            int cl = cg * 16 + grp * 4 + r;
            #pragma unroll
            for (int j = 0; j < 8; ++j) {
                int c = cq * 128 + j * 16 + col;
                sm.e.vbuf[cl * CC + c] = f2bf(acc[j][r] * vinv);
            }
        }
    }
    LB();

    // FC: NCLS dots of length 32768
    float pacc[NCLS] = {0.f, 0.f, 0.f, 0.f};
    #pragma unroll
    for (int i = 0; i < 4; ++i) {
        int idx = i * 8192 + tid * 8;
        bf16x8 vv = *(const bf16x8*)&sm.e.vbuf[idx];
        float vf[8];
        #pragma unroll
        for (int h = 0; h < 8; ++h) {
            union { unsigned int u; float f; } cvt;
            cvt.u = ((unsigned int)(unsigned short)vv[h]) << 16;
            vf[h] = cvt.f;
        }
        #pragma unroll
        for (int nc = 0; nc < NCLS; ++nc) {
            const float* wp = fcw + (size_t)nc * (KK * CC) + idx;
            float4 w0 = *(const float4*)wp;
            float4 w1 = *(const float4*)(wp + 4);
            pacc[nc] += vf[0] * w0.x + vf[1] * w0.y + vf[2] * w0.z + vf[3] * w0.w
                      + vf[4] * w1.x + vf[5] * w1.y + vf[6] * w1.z + vf[7] * w1.w;
        }
    }
    #pragma unroll
    for (int nc = 0; nc < NCLS; ++nc) {
        #pragma unroll
        for (int m = 1; m < 64; m <<= 1) pacc[nc] += __shfl_xor(pacc[nc], m);
    }
    if (lane == 0) {
        #pragma unroll
        for (int nc = 0; nc < NCLS; ++nc) fcred[w][nc] = pacc[nc];
    }
    LB();
    if (tid < NCLS) {
        float s = fcb[tid];
        #pragma unroll
        for (int ww = 0; ww < 16; ++ww) s += fcred[ww][tid];
        out[b * NCLS + tid] = 1.f / (1.f + __expf(-s));
    }
}

extern "C" void kernel_launch(void* const* d_in, const int* in_sizes, int n_in,
                              void* d_out, int out_size, void* d_ws, size_t ws_size,
                              hipStream_t stream) {
    const float* inp   = (const float*)d_in[0];
    const float* convw = (const float*)d_in[1];
    const float* cent  = (const float*)d_in[2];
    const float* fcw   = (const float*)d_in[3];
    const float* fcb   = (const float*)d_in[4];
    float* o = (float*)d_out;
    netvlad_kernel<<<BB, THREADS, 0, stream>>>(inp, convw, cent, fcw, fcb, o);
}